// Round 18
// baseline (76.796 us; speedup 1.0000x reference)
//
#include <hip/hip_runtime.h>
#include <hip/hip_fp16.h>

#define NREL1  12   // NREL + 1 relation matrices
#define NN     128  // neighbours
#define EE     128  // in-features
#define FF     128  // out-features
#define BV     192  // B * V
#define RK     (NREL1 * EE)   // 1536
#define NREP   3    // DIAGNOSTIC: x3 repeat of the post-prefetch body

// ws layout (floats):
//   [0, 3072)        wa  (Wa1[12][128] | Wa2[12][128])
//   [4096, 102400)   W_h: W converted to __half, [k][f] row-major
#define WS_WA  0
#define WS_WH  4096

// K0: wa rows (wave per (r,e), coalesced W read once aggregate) + W->fp16.
__global__ __launch_bounds__(256) void prep_kernel(const float* __restrict__ W,
                                                   const float* __restrict__ a,
                                                   float* __restrict__ ws) {
    const int w    = blockIdx.x * 4 + (threadIdx.x >> 6);  // 1536 waves
    const int lane = threadIdx.x & 63;
    const int r = w >> 7, e = w & 127;
    const float2 wv = *(const float2*)(W + (size_t)(r * EE + e) * FF + lane * 2);
    const float2 a1 = *(const float2*)(a + lane * 2);
    const float2 a2 = *(const float2*)(a + FF + lane * 2);
    float d1 = wv.x * a1.x + wv.y * a1.y;
    float d2 = wv.x * a2.x + wv.y * a2.y;
#pragma unroll
    for (int off = 32; off; off >>= 1) {
        d1 += __shfl_xor(d1, off);
        d2 += __shfl_xor(d2, off);
    }
    if (lane == 0) {
        ws[WS_WA + r * EE + e]      = d1;
        ws[WS_WA + RK + r * EE + e] = d2;
    }
    // W -> fp16 (each thread converts 2 consecutive floats)
    const int gid = blockIdx.x * 256 + threadIdx.x;   // 98304 threads
    const float2 wv2 = *(const float2*)(W + (size_t)2 * gid);
    ((__half2*)(ws + WS_WH))[gid] = __float22half2_rn(wv2);
}

// K1 DIAGNOSTIC: identical to R17 but the post-prefetch body repeats NREP
// times (idempotent; same out written each rep). Prefetch (HBM) runs once.
// T_x3 - T_single isolates compute-phase cost; the long dispatch surfaces
// VALUBusy / bank-conflict / occupancy counters for this exact code shape.
__global__ __launch_bounds__(1024) void gat_fused(const float* __restrict__ fe,
                                                  const float* __restrict__ ne,
                                                  const int* __restrict__ widx,
                                                  const float* __restrict__ ind,
                                                  const float* __restrict__ ws_r,
                                                  float* __restrict__ out) {
    __shared__ float wa[2 * RK];     // 12 KB
    __shared__ float s16[16][RK];    // 96 KB; s16[0] holds S after reduce
    __shared__ float red[32][FF];    // 16 KB
    __shared__ float red2[4][FF];    // 2 KB
    __shared__ float e_lds[NN];      // 0.5 KB

    const int bv   = blockIdx.x;
    const int tid  = threadIdx.x;
    const int wave = tid >> 6;
    const int lane = tid & 63;
    const int l32  = lane & 31;
    const int half = lane >> 5;   // which edge of each pair this lane owns

    const float* ne_bv = ne + (size_t)bv * NN * EE;
    const float* fe_bv = fe + (size_t)bv * NN * EE;

    // prefetch: 4 edge-pairs per wave; lane holds ne AND fe quads of ITS edge
    float4 xn[4], xf[4];
    int    rr[4];
#pragma unroll
    for (int i = 0; i < 4; ++i) {
        const int n = wave * 8 + i * 2 + half;
        xn[i] = *(const float4*)(ne_bv + (size_t)n * EE + l32 * 4);
        xf[i] = *(const float4*)(fe_bv + (size_t)n * EE + l32 * 4);
        rr[i] = widx[bv * NN + n];          // half-uniform -> broadcast load
    }
    const float iv0 = ind[bv * NN + lane];
    const float iv1 = ind[bv * NN + lane + 64];

    // stage wa (L2) -> LDS once (outside rep loop; read-only thereafter)
    if (tid < 2 * RK / 4)
        ((float4*)wa)[tid] = ((const float4*)(ws_r + WS_WA))[tid];

    for (int rep = 0; rep < NREP; ++rep) {
        asm volatile("" ::: "memory");   // pin the repeat (no cross-rep CSE)
        __syncthreads();

        // zero scatter copies (6 float4/thread)
        {
            const float4 z = {0.f, 0.f, 0.f, 0.f};
#pragma unroll
            for (int q = 0; q < 6; ++q)
                ((float4*)&s16[0][0])[q * 1024 + tid] = z;
        }
        __syncthreads();

        // Phase A: logits, 2 edges per 5-step butterfly (halves independent)
#pragma unroll
        for (int i = 0; i < 4; ++i) {
            const int n = wave * 8 + i * 2 + half;
            const float4 w1 = *(const float4*)&wa[rr[i] * EE + l32 * 4];
            const float4 w2 = *(const float4*)&wa[RK + rr[i] * EE + l32 * 4];
            float d = xn[i].x * w1.x + xn[i].y * w1.y + xn[i].z * w1.z + xn[i].w * w1.w
                    + xf[i].x * w2.x + xf[i].y * w2.y + xf[i].z * w2.z + xf[i].w * w2.w;
#pragma unroll
            for (int off = 1; off <= 16; off <<= 1) d += __shfl_xor(d, off);
            if (l32 == 0) e_lds[n] = d > 0.f ? d : 0.2f * d;
        }
        __syncthreads();

        // Phase B: per-wave redundant softmax + indicator, registers only
        float a0, a1;
        {
            const float v0 = e_lds[lane], v1 = e_lds[lane + 64];
            float m = fmaxf(v0, v1);
#pragma unroll
            for (int off = 32; off; off >>= 1) m = fmaxf(m, __shfl_xor(m, off));
            const float ex0 = __expf(v0 - m), ex1 = __expf(v1 - m);
            float ss = ex0 + ex1;
#pragma unroll
            for (int off = 32; off; off >>= 1) ss += __shfl_xor(ss, off);
            const float inv = 1.f / ss;
            a0 = ex0 * inv * iv0;
            a1 = ex1 * inv * iv1;
        }

        // attn broadcast for my 4 edges: ALL 64 lanes participate
        float anv[4];
#pragma unroll
        for (int i = 0; i < 4; ++i) {
            const int n = wave * 8 + i * 2 + half;
            anv[i] = (wave < 8) ? __shfl(a0, n) : __shfl(a1, n - 64);
        }

        // Phase C: scatter into this wave's private copy; real barrier
        // between the half-0 and half-1 RMW blocks (R16 lesson).
        {
            float* sc = s16[wave];
            if (half == 0) {
#pragma unroll
                for (int i = 0; i < 4; ++i) {
                    float* p = sc + rr[i] * EE + l32 * 4;
                    float4 cur = *(const float4*)p;
                    cur.x += anv[i] * xn[i].x; cur.y += anv[i] * xn[i].y;
                    cur.z += anv[i] * xn[i].z; cur.w += anv[i] * xn[i].w;
                    *(float4*)p = cur;
                }
            }
            __syncthreads();
            if (half == 1) {
#pragma unroll
                for (int i = 0; i < 4; ++i) {
                    float* p = sc + rr[i] * EE + l32 * 4;
                    float4 cur = *(const float4*)p;
                    cur.x += anv[i] * xn[i].x; cur.y += anv[i] * xn[i].y;
                    cur.z += anv[i] * xn[i].z; cur.w += anv[i] * xn[i].w;
                    *(float4*)p = cur;
                }
            }
        }
        __syncthreads();

        // reduce 16 copies -> S in s16[0] (in place)
        if (tid < RK / 4) {
            float4 v = *(const float4*)&s16[0][tid * 4];
#pragma unroll
            for (int c = 1; c < 16; ++c) {
                const float4 t = *(const float4*)&s16[c][tid * 4];
                v.x += t.x; v.y += t.y; v.z += t.z; v.w += t.w;
            }
            *(float4*)&s16[0][tid * 4] = v;
        }
        __syncthreads();

        // Phase D: out[bv][f] = sum_k S[k] * W_h[k][f]  (fp16 W, fp32 acc)
        {
            const int fq = tid & 31;
            const int kg = tid >> 5;
            float4 sreg[12];
#pragma unroll
            for (int j = 0; j < 12; ++j)
                sreg[j] = *(const float4*)&s16[0][kg * 48 + j * 4];

            const __half* Wh = (const __half*)(ws_r + WS_WH);
            const __half* Wp = Wh + (size_t)(kg * 48) * FF + fq * 4;
            float4 acc = {0.f, 0.f, 0.f, 0.f};
#pragma unroll
            for (int j = 0; j < 12; ++j) {
#pragma unroll
                for (int u = 0; u < 4; ++u) {
                    const float sv = (u == 0) ? sreg[j].x : (u == 1) ? sreg[j].y
                                   : (u == 2) ? sreg[j].z : sreg[j].w;
                    const float2 raw = *(const float2*)(Wp + (size_t)(j * 4 + u) * FF);
                    const __half2* hp = (const __half2*)&raw;
                    const float2 f01 = __half22float2(hp[0]);
                    const float2 f23 = __half22float2(hp[1]);
                    acc.x += sv * f01.x; acc.y += sv * f01.y;
                    acc.z += sv * f23.x; acc.w += sv * f23.y;
                }
            }
            *(float4*)&red[kg][fq * 4] = acc;
        }
        __syncthreads();
        if (tid < 512) {
            const int f = tid & 127, h = tid >> 7;
            float v = 0.f;
#pragma unroll
            for (int j = 0; j < 8; ++j) v += red[h * 8 + j][f];
            red2[h][f] = v;
        }
        __syncthreads();
        if (tid < FF)
            out[bv * FF + tid] = red2[0][tid] + red2[1][tid] + red2[2][tid] + red2[3][tid];
    }
}

extern "C" void kernel_launch(void* const* d_in, const int* in_sizes, int n_in,
                              void* d_out, int out_size, void* d_ws, size_t ws_size,
                              hipStream_t stream) {
    const float* fe  = (const float*)d_in[0];  // feature_embed   (B,V,N,E)
    const float* ne  = (const float*)d_in[1];  // neighbour_embed (B,V,N,E)
    const int*   wi  = (const int*)d_in[2];    // w_index (B,V,N)
    const float* ind = (const float*)d_in[3];  // indicator (B,V,N)
    const float* W   = (const float*)d_in[4];  // (12,E,F)
    const float* a   = (const float*)d_in[5];  // (2F,1)
    float* out = (float*)d_out;                // (B,V,F)
    float* ws  = (float*)d_ws;

    prep_kernel<<<RK / 4, 256, 0, stream>>>(W, a, ws);
    gat_fused<<<BV, 1024, 0, stream>>>(fe, ne, wi, ind, ws, out);
}

// Round 19
// 21.848 us; speedup vs baseline: 3.5150x; 3.5150x over previous
//
#include <hip/hip_runtime.h>
#include <hip/hip_fp16.h>

#define NREL1  12   // NREL + 1 relation matrices
#define NN     128  // neighbours
#define EE     128  // in-features
#define FF     128  // out-features
#define BV     192  // B * V
#define RK     (NREL1 * EE)   // 1536

// ws layout (floats):
//   [0, 3072)        wa  (Wa1[12][128] | Wa2[12][128])
//   [4096, 102400)   W_h: W converted to __half, [k][f] row-major
#define WS_WA  0
#define WS_WH  4096

// K0: wa rows (wave per (r,e), coalesced W read once aggregate) + W->fp16.
__global__ __launch_bounds__(256) void prep_kernel(const float* __restrict__ W,
                                                   const float* __restrict__ a,
                                                   float* __restrict__ ws) {
    const int w    = blockIdx.x * 4 + (threadIdx.x >> 6);  // 1536 waves
    const int lane = threadIdx.x & 63;
    const int r = w >> 7, e = w & 127;
    const float2 wv = *(const float2*)(W + (size_t)(r * EE + e) * FF + lane * 2);
    const float2 a1 = *(const float2*)(a + lane * 2);
    const float2 a2 = *(const float2*)(a + FF + lane * 2);
    float d1 = wv.x * a1.x + wv.y * a1.y;
    float d2 = wv.x * a2.x + wv.y * a2.y;
#pragma unroll
    for (int off = 32; off; off >>= 1) {
        d1 += __shfl_xor(d1, off);
        d2 += __shfl_xor(d2, off);
    }
    if (lane == 0) {
        ws[WS_WA + r * EE + e]      = d1;
        ws[WS_WA + RK + r * EE + e] = d2;
    }
    // W -> fp16 (each thread converts 2 consecutive floats)
    const int gid = blockIdx.x * 256 + threadIdx.x;   // 98304 threads
    const float2 wv2 = *(const float2*)(W + (size_t)2 * gid);
    ((__half2*)(ws + WS_WH))[gid] = __float22half2_rn(wv2);
}

// K1: block per bv, 1024 threads (16 waves). R17 structure + per-block edge
// ROTATION: block bv sweeps edges starting at rot=(bv*38)&127 so the 192
// simultaneous fe/ne streams start at 64 distinct 1-KB offsets instead of
// all at their 64-KB-aligned bases (HBM channel camping fix). rot is even ->
// edge pairs never straddle the 63/64 boundary (attn-select stays uniform).
__global__ __launch_bounds__(1024) void gat_fused(const float* __restrict__ fe,
                                                  const float* __restrict__ ne,
                                                  const int* __restrict__ widx,
                                                  const float* __restrict__ ind,
                                                  const float* __restrict__ ws_r,
                                                  float* __restrict__ out) {
    __shared__ float wa[2 * RK];     // 12 KB
    __shared__ float s16[16][RK];    // 96 KB; s16[0] holds S after reduce
    __shared__ float red[32][FF];    // 16 KB
    __shared__ float red2[4][FF];    // 2 KB
    __shared__ float e_lds[NN];      // 0.5 KB

    const int bv   = blockIdx.x;
    const int tid  = threadIdx.x;
    const int wave = tid >> 6;
    const int lane = tid & 63;
    const int l32  = lane & 31;
    const int half = lane >> 5;   // which edge of each pair this lane owns
    const int rot  = (bv * 38) & 127;   // even rotation, bijective

    const float* ne_bv = ne + (size_t)bv * NN * EE;
    const float* fe_bv = fe + (size_t)bv * NN * EE;

    // prefetch: 4 edge-pairs per wave at rotated positions
    float4 xn[4], xf[4];
    int    rr[4];
#pragma unroll
    for (int i = 0; i < 4; ++i) {
        const int n = (wave * 8 + i * 2 + half + rot) & 127;
        xn[i] = *(const float4*)(ne_bv + (size_t)n * EE + l32 * 4);
        xf[i] = *(const float4*)(fe_bv + (size_t)n * EE + l32 * 4);
        rr[i] = widx[bv * NN + n];          // half-uniform -> broadcast load
    }
    const float iv0 = ind[bv * NN + lane];
    const float iv1 = ind[bv * NN + lane + 64];

    // stage wa (L2) -> LDS (1 float4/thread); zero scatter copies (6/thread)
    if (tid < 2 * RK / 4)
        ((float4*)wa)[tid] = ((const float4*)(ws_r + WS_WA))[tid];
    {
        const float4 z = {0.f, 0.f, 0.f, 0.f};
#pragma unroll
        for (int q = 0; q < 6; ++q)
            ((float4*)&s16[0][0])[q * 1024 + tid] = z;
    }
    __syncthreads();

    // Phase A: logits, 2 edges per 5-step butterfly (halves independent)
#pragma unroll
    for (int i = 0; i < 4; ++i) {
        const int n = (wave * 8 + i * 2 + half + rot) & 127;
        const float4 w1 = *(const float4*)&wa[rr[i] * EE + l32 * 4];
        const float4 w2 = *(const float4*)&wa[RK + rr[i] * EE + l32 * 4];
        float d = xn[i].x * w1.x + xn[i].y * w1.y + xn[i].z * w1.z + xn[i].w * w1.w
                + xf[i].x * w2.x + xf[i].y * w2.y + xf[i].z * w2.z + xf[i].w * w2.w;
#pragma unroll
        for (int off = 1; off <= 16; off <<= 1) d += __shfl_xor(d, off);
        if (l32 == 0) e_lds[n] = d > 0.f ? d : 0.2f * d;
    }
    __syncthreads();

    // Phase B: per-wave redundant softmax + indicator, registers only
    float a0, a1;
    {
        const float v0 = e_lds[lane], v1 = e_lds[lane + 64];
        float m = fmaxf(v0, v1);
#pragma unroll
        for (int off = 32; off; off >>= 1) m = fmaxf(m, __shfl_xor(m, off));
        const float ex0 = __expf(v0 - m), ex1 = __expf(v1 - m);
        float ss = ex0 + ex1;
#pragma unroll
        for (int off = 32; off; off >>= 1) ss += __shfl_xor(ss, off);
        const float inv = 1.f / ss;
        a0 = ex0 * inv * iv0;
        a1 = ex1 * inv * iv1;
    }

    // attn broadcast for my 4 edges: ALL 64 lanes participate (R13 lesson).
    // n < 64 is wave-uniform because rot is even (pairs stay in one group).
    float anv[4];
#pragma unroll
    for (int i = 0; i < 4; ++i) {
        const int n = (wave * 8 + i * 2 + half + rot) & 127;
        anv[i] = (n < 64) ? __shfl(a0, n) : __shfl(a1, n - 64);
    }

    // Phase C: scatter into this wave's private copy; real barrier between
    // the half-0 and half-1 RMW blocks (R16 lesson: identical predicated
    // bodies get merged by the compiler -> race).
    {
        float* sc = s16[wave];
        if (half == 0) {
#pragma unroll
            for (int i = 0; i < 4; ++i) {
                float* p = sc + rr[i] * EE + l32 * 4;
                float4 cur = *(const float4*)p;
                cur.x += anv[i] * xn[i].x; cur.y += anv[i] * xn[i].y;
                cur.z += anv[i] * xn[i].z; cur.w += anv[i] * xn[i].w;
                *(float4*)p = cur;
            }
        }
        __syncthreads();   // order half-0 RMWs before half-1 RMWs
        if (half == 1) {
#pragma unroll
            for (int i = 0; i < 4; ++i) {
                float* p = sc + rr[i] * EE + l32 * 4;
                float4 cur = *(const float4*)p;
                cur.x += anv[i] * xn[i].x; cur.y += anv[i] * xn[i].y;
                cur.z += anv[i] * xn[i].z; cur.w += anv[i] * xn[i].w;
                *(float4*)p = cur;
            }
        }
    }
    __syncthreads();

    // reduce 16 copies -> S in s16[0] (in place)
    if (tid < RK / 4) {
        float4 v = *(const float4*)&s16[0][tid * 4];
#pragma unroll
        for (int c = 1; c < 16; ++c) {
            const float4 t = *(const float4*)&s16[c][tid * 4];
            v.x += t.x; v.y += t.y; v.z += t.z; v.w += t.w;
        }
        *(float4*)&s16[0][tid * 4] = v;
    }
    __syncthreads();

    // Phase D: out[bv][f] = sum_k S[k] * W_h[k][f]  (fp16 W, fp32 acc)
    {
        const int fq = tid & 31;
        const int kg = tid >> 5;
        float4 sreg[12];
#pragma unroll
        for (int j = 0; j < 12; ++j)
            sreg[j] = *(const float4*)&s16[0][kg * 48 + j * 4];

        const __half* Wh = (const __half*)(ws_r + WS_WH);
        const __half* Wp = Wh + (size_t)(kg * 48) * FF + fq * 4;
        float4 acc = {0.f, 0.f, 0.f, 0.f};
#pragma unroll
        for (int j = 0; j < 12; ++j) {
#pragma unroll
            for (int u = 0; u < 4; ++u) {
                const float sv = (u == 0) ? sreg[j].x : (u == 1) ? sreg[j].y
                               : (u == 2) ? sreg[j].z : sreg[j].w;
                const float2 raw = *(const float2*)(Wp + (size_t)(j * 4 + u) * FF);
                const __half2* hp = (const __half2*)&raw;
                const float2 f01 = __half22float2(hp[0]);
                const float2 f23 = __half22float2(hp[1]);
                acc.x += sv * f01.x; acc.y += sv * f01.y;
                acc.z += sv * f23.x; acc.w += sv * f23.y;
            }
        }
        *(float4*)&red[kg][fq * 4] = acc;
    }
    __syncthreads();
    if (tid < 512) {
        const int f = tid & 127, h = tid >> 7;
        float v = 0.f;
#pragma unroll
        for (int j = 0; j < 8; ++j) v += red[h * 8 + j][f];
        red2[h][f] = v;
    }
    __syncthreads();
    if (tid < FF)
        out[bv * FF + tid] = red2[0][tid] + red2[1][tid] + red2[2][tid] + red2[3][tid];
}

extern "C" void kernel_launch(void* const* d_in, const int* in_sizes, int n_in,
                              void* d_out, int out_size, void* d_ws, size_t ws_size,
                              hipStream_t stream) {
    const float* fe  = (const float*)d_in[0];  // feature_embed   (B,V,N,E)
    const float* ne  = (const float*)d_in[1];  // neighbour_embed (B,V,N,E)
    const int*   wi  = (const int*)d_in[2];    // w_index (B,V,N)
    const float* ind = (const float*)d_in[3];  // indicator (B,V,N)
    const float* W   = (const float*)d_in[4];  // (12,E,F)
    const float* a   = (const float*)d_in[5];  // (2F,1)
    float* out = (float*)d_out;                // (B,V,F)
    float* ws  = (float*)d_ws;

    prep_kernel<<<RK / 4, 256, 0, stream>>>(W, a, ws);
    gat_fused<<<BV, 1024, 0, stream>>>(fe, ne, wi, ind, ws, out);
}